// Round 1
// baseline (346.646 us; speedup 1.0000x reference)
//
#include <hip/hip_runtime.h>
#include <float.h>

#define BB 16
#define CC 64
#define NN 2048
#define KNN 3
#define COUT 64
#define SPLIT 4
#define MRANGE (NN / SPLIT)
#define TM 128

// ---------------------------------------------------------------------------
// K1: transpose x[b][c][n] -> xt[b][n][c] (LDS tile) + per-point squared norms
// ---------------------------------------------------------------------------
__global__ __launch_bounds__(256) void k_prep(const float* __restrict__ x,
                                              float* __restrict__ xt,
                                              float* __restrict__ nrm) {
    __shared__ float t[64][65];  // +1 pad: conflict-free transposed reads
    const int b = blockIdx.x;
    const int n0 = blockIdx.y * 64;
    const int tid = threadIdx.x;
    const int ln = tid & 63, g = tid >> 6;
#pragma unroll
    for (int i = 0; i < 16; ++i) {
        const int c = g + 4 * i;
        t[c][ln] = x[((size_t)b * CC + c) * NN + n0 + ln];  // coalesced over n
    }
    __syncthreads();
#pragma unroll
    for (int i = 0; i < 16; ++i) {
        const int nl = g + 4 * i;
        xt[((size_t)b * NN + n0 + nl) * CC + ln] = t[ln][nl];  // coalesced over c
    }
    if (tid < 64) {
        float s = 0.f;
#pragma unroll
        for (int c = 0; c < 64; ++c) s = fmaf(t[c][tid], t[c][tid], s);
        nrm[(size_t)b * NN + n0 + tid] = s;
    }
}

// ---------------------------------------------------------------------------
// K2: per query point, top-3 smallest distances over an m-range (SPLIT-way).
// One thread = one query. dist = (norm_n + norm_m) - 2*dot  (reference formula)
// Strict < comparisons + ascending m  ==  lax.top_k lower-index tie-break.
// ---------------------------------------------------------------------------
__global__ __launch_bounds__(256) void k_top3(const float* __restrict__ xt,
                                              const float* __restrict__ nrm,
                                              float* __restrict__ pd,
                                              int* __restrict__ pi) {
    __shared__ float mt[TM][64];  // staged candidate tile (32 KB)
    __shared__ float mn[TM];
    const int b = blockIdx.x;
    const int tid = threadIdx.x;
    const int n = blockIdx.y * 256 + tid;
    const int s = blockIdx.z;

    float4 q[16];
    const float4* qp = (const float4*)(xt + ((size_t)b * NN + n) * CC);
#pragma unroll
    for (int i = 0; i < 16; ++i) q[i] = qp[i];
    const float sn = nrm[(size_t)b * NN + n];

    float d0 = FLT_MAX, d1 = FLT_MAX, d2 = FLT_MAX;
    int i0 = -1, i1 = -1, i2 = -1;

    for (int t0 = 0; t0 < MRANGE; t0 += TM) {
        const int mb = s * MRANGE + t0;
        __syncthreads();
#pragma unroll
        for (int i = 0; i < 8; ++i) {  // stage 128x64 f32, coalesced
            const int t = tid + i * 256;
            const int row = t >> 4, c4 = t & 15;
            ((float4*)mt[row])[c4] =
                ((const float4*)(xt + ((size_t)b * NN + mb + row) * CC))[c4];
        }
        if (tid < TM) mn[tid] = nrm[(size_t)b * NN + mb + tid];
        __syncthreads();

        for (int mm = 0; mm < TM; ++mm) {
            const float4* mp = (const float4*)mt[mm];  // broadcast reads
            float a0 = 0.f, a1 = 0.f, a2 = 0.f, a3 = 0.f;
#pragma unroll
            for (int i = 0; i < 16; ++i) {
                const float4 mv = mp[i];
                a0 = fmaf(q[i].x, mv.x, a0);
                a1 = fmaf(q[i].y, mv.y, a1);
                a2 = fmaf(q[i].z, mv.z, a2);
                a3 = fmaf(q[i].w, mv.w, a3);
            }
            const float dot = (a0 + a1) + (a2 + a3);
            const float d = fmaf(-2.f, dot, sn + mn[mm]);
            const int m = mb + mm;
            // branchless sorted-insert, strict < keeps lower-index-first ties
            const bool lt0 = d < d0, lt1 = d < d1, lt2 = d < d2;
            d2 = lt1 ? d1 : (lt2 ? d : d2);
            i2 = lt1 ? i1 : (lt2 ? m : i2);
            d1 = lt0 ? d0 : (lt1 ? d : d1);
            i1 = lt0 ? i0 : (lt1 ? m : i1);
            d0 = lt0 ? d : d0;
            i0 = lt0 ? m : i0;
        }
    }
    const size_t o = (((size_t)b * SPLIT + s) * NN + n) * 3;
    pd[o] = d0; pd[o + 1] = d1; pd[o + 2] = d2;
    pi[o] = i0; pi[o + 1] = i1; pi[o + 2] = i2;
}

// ---------------------------------------------------------------------------
// K3: merge SPLIT sorted top-3 lists -> final 3 indices, (d, idx) lexicographic
// Static indexing only (unrolled) so arrays stay in registers.
// ---------------------------------------------------------------------------
__global__ __launch_bounds__(256) void k_merge(const float* __restrict__ pd,
                                               const int* __restrict__ pi,
                                               int* __restrict__ fi) {
    const int t = blockIdx.x * 256 + threadIdx.x;
    if (t >= BB * NN) return;
    const int b = t / NN, n = t % NN;
    float dv[12]; int iv[12];
#pragma unroll
    for (int s = 0; s < SPLIT; ++s) {
        const size_t o = (((size_t)b * SPLIT + s) * NN + n) * 3;
#pragma unroll
        for (int r = 0; r < 3; ++r) {
            dv[s * 3 + r] = pd[o + r];
            iv[s * 3 + r] = pi[o + r];
        }
    }
    float bd = -FLT_MAX; int bi = -1;
#pragma unroll
    for (int r = 0; r < 3; ++r) {
        float cd = FLT_MAX; int ci = 0x7fffffff;
#pragma unroll
        for (int j = 0; j < 12; ++j) {
            const bool gt_prev = (dv[j] > bd) || (dv[j] == bd && iv[j] > bi);
            const bool lt_cur = (dv[j] < cd) || (dv[j] == cd && iv[j] < ci);
            if (gt_prev && lt_cur) { cd = dv[j]; ci = iv[j]; }
        }
        fi[(size_t)t * 3 + r] = ci;
        bd = cd; bi = ci;
    }
}

// ---------------------------------------------------------------------------
// K4: gather neighbors (L2-resident xt rows) + 1x3/stride-3 conv + bias + relu
// W in LDS as [k][c][co] -> broadcast float4 reads; 16 outputs per thread;
// stores coalesced over n.
// ---------------------------------------------------------------------------
__global__ __launch_bounds__(256) void k_conv(const float* __restrict__ xt,
                                              const int* __restrict__ fi,
                                              const float* __restrict__ W,
                                              const float* __restrict__ bias,
                                              float* __restrict__ out) {
    __shared__ float Wl[KNN][CC][COUT];  // 48 KB
    const int b = blockIdx.x, n0 = blockIdx.y * 64;
    const int tid = threadIdx.x;
    const int nl = tid & 63, g = tid >> 6;
    for (int t = tid; t < COUT * CC * KNN; t += 256) {
        const int co = t / (CC * KNN);
        const int rem = t % (CC * KNN);
        const int c = rem / KNN, k = rem % KNN;
        Wl[k][c][co] = W[t];
    }
    __syncthreads();

    const int cobase = g * 16;
    float4 acc[4];
#pragma unroll
    for (int j = 0; j < 4; ++j) acc[j] = *(const float4*)&bias[cobase + j * 4];

    const size_t fbase = ((size_t)b * NN + n0 + nl) * 3;
#pragma unroll
    for (int k = 0; k < KNN; ++k) {
        const int src = fi[fbase + k];
        const float4* vrow = (const float4*)(xt + ((size_t)b * NN + src) * CC);
#pragma unroll
        for (int c4 = 0; c4 < 16; ++c4) {
            const float4 p = vrow[c4];
#pragma unroll
            for (int cp = 0; cp < 4; ++cp) {
                const float pv = (&p.x)[cp];
                const float4* wr = (const float4*)&Wl[k][c4 * 4 + cp][cobase];
#pragma unroll
                for (int j = 0; j < 4; ++j) {
                    const float4 w = wr[j];
                    acc[j].x = fmaf(pv, w.x, acc[j].x);
                    acc[j].y = fmaf(pv, w.y, acc[j].y);
                    acc[j].z = fmaf(pv, w.z, acc[j].z);
                    acc[j].w = fmaf(pv, w.w, acc[j].w);
                }
            }
        }
    }
#pragma unroll
    for (int j = 0; j < 4; ++j) {
#pragma unroll
        for (int cp = 0; cp < 4; ++cp) {
            const int co = cobase + j * 4 + cp;
            const float v = fmaxf((&acc[j].x)[cp], 0.f);
            out[((size_t)b * COUT + co) * NN + n0 + nl] = v;
        }
    }
}

extern "C" void kernel_launch(void* const* d_in, const int* in_sizes, int n_in,
                              void* d_out, int out_size, void* d_ws, size_t ws_size,
                              hipStream_t stream) {
    const float* x = (const float*)d_in[0];
    const float* W = (const float*)d_in[1];
    const float* bias = (const float*)d_in[2];
    float* out = (float*)d_out;

    char* ws = (char*)d_ws;
    float* xt = (float*)(ws);                  // 8,388,608 B
    float* nrm = (float*)(ws + 8388608);       //   131,072 B
    float* pd = (float*)(ws + 8519680);        // 1,572,864 B
    int* pi = (int*)(ws + 10092544);           // 1,572,864 B
    int* fi = (int*)(ws + 11665408);           //   393,216 B  (total ~11.5 MB)

    k_prep<<<dim3(BB, NN / 64), 256, 0, stream>>>(x, xt, nrm);
    k_top3<<<dim3(BB, NN / 256, SPLIT), 256, 0, stream>>>(xt, nrm, pd, pi);
    k_merge<<<(BB * NN + 255) / 256, 256, 0, stream>>>(pd, pi, fi);
    k_conv<<<dim3(BB, NN / 64), 256, 0, stream>>>(xt, fi, W, bias, out);
}

// Round 2
// 202.685 us; speedup vs baseline: 1.7103x; 1.7103x over previous
//
#include <hip/hip_runtime.h>
#include <float.h>

#define BB 16
#define CC 64
#define NN 2048
#define KNN 3
#define COUT 64
#define SPLIT 8
#define MRANGE (NN / SPLIT)  // 256
#define TM 128
#define QT 2                 // queries per thread

// ---------------------------------------------------------------------------
// K1: transpose x[b][c][n] -> xt[b][n][c] (LDS tile) + per-point squared norms
// ---------------------------------------------------------------------------
__global__ __launch_bounds__(256) void k_prep(const float* __restrict__ x,
                                              float* __restrict__ xt,
                                              float* __restrict__ nrm) {
    __shared__ float t[64][65];
    const int b = blockIdx.x;
    const int n0 = blockIdx.y * 64;
    const int tid = threadIdx.x;
    const int ln = tid & 63, g = tid >> 6;
#pragma unroll
    for (int i = 0; i < 16; ++i) {
        const int c = g + 4 * i;
        t[c][ln] = x[((size_t)b * CC + c) * NN + n0 + ln];
    }
    __syncthreads();
#pragma unroll
    for (int i = 0; i < 16; ++i) {
        const int nl = g + 4 * i;
        xt[((size_t)b * NN + n0 + nl) * CC + ln] = t[ln][nl];
    }
    if (tid < 64) {
        float s = 0.f;
#pragma unroll
        for (int c = 0; c < 64; ++c) s = fmaf(t[c][tid], t[c][tid], s);
        nrm[(size_t)b * NN + n0 + tid] = s;
    }
}

// ---------------------------------------------------------------------------
// K2: top-3 over an m-range; 2 queries per thread (halves LDS reads per FMA),
// explicit cv[16] batch load = 16 ds_read_b128 in flight, early-out insert.
// dist = fmaf(-2, dot, sn + mn)  (same rounding as the passing round-1 code)
// ---------------------------------------------------------------------------
__global__ __launch_bounds__(256, 2) void k_top3(const float* __restrict__ xt,
                                                 const float* __restrict__ nrm,
                                                 float* __restrict__ pd,
                                                 int* __restrict__ pi) {
    __shared__ float mt[TM][64];  // 32 KB candidate tile
    __shared__ float mn[TM];
    const int b = blockIdx.x;
    const int tid = threadIdx.x;
    const int nA = blockIdx.y * (256 * QT) + tid;
    const int nB = nA + 256;
    const int s = blockIdx.z;

    float4 qA[16], qB[16];
    const float4* pA = (const float4*)(xt + ((size_t)b * NN + nA) * CC);
    const float4* pB = (const float4*)(xt + ((size_t)b * NN + nB) * CC);
#pragma unroll
    for (int i = 0; i < 16; ++i) qA[i] = pA[i];
#pragma unroll
    for (int i = 0; i < 16; ++i) qB[i] = pB[i];
    const float snA = nrm[(size_t)b * NN + nA];
    const float snB = nrm[(size_t)b * NN + nB];

    float dA0 = FLT_MAX, dA1 = FLT_MAX, dA2 = FLT_MAX;
    float dB0 = FLT_MAX, dB1 = FLT_MAX, dB2 = FLT_MAX;
    int iA0 = -1, iA1 = -1, iA2 = -1;
    int iB0 = -1, iB1 = -1, iB2 = -1;

    for (int t0 = 0; t0 < MRANGE; t0 += TM) {
        const int mb = s * MRANGE + t0;
        __syncthreads();
#pragma unroll
        for (int i = 0; i < 8; ++i) {  // stage 128x64 f32, coalesced
            const int t = tid + i * 256;
            const int row = t >> 4, c4 = t & 15;
            ((float4*)mt[row])[c4] =
                ((const float4*)(xt + ((size_t)b * NN + mb + row) * CC))[c4];
        }
        if (tid < TM) mn[tid] = nrm[(size_t)b * NN + mb + tid];
        __syncthreads();

        for (int mm = 0; mm < TM; ++mm) {
            const float4* mp = (const float4*)mt[mm];  // wave-uniform broadcast
            float4 cv[16];
#pragma unroll
            for (int i = 0; i < 16; ++i) cv[i] = mp[i];  // 16 b128 in flight
            const float smn = mn[mm];
            float a0 = 0.f, a1 = 0.f, a2 = 0.f, a3 = 0.f;
            float b0 = 0.f, b1 = 0.f, b2 = 0.f, b3 = 0.f;
#pragma unroll
            for (int i = 0; i < 16; ++i) {
                const float4 c = cv[i];
                a0 = fmaf(qA[i].x, c.x, a0);
                a1 = fmaf(qA[i].y, c.y, a1);
                a2 = fmaf(qA[i].z, c.z, a2);
                a3 = fmaf(qA[i].w, c.w, a3);
                b0 = fmaf(qB[i].x, c.x, b0);
                b1 = fmaf(qB[i].y, c.y, b1);
                b2 = fmaf(qB[i].z, c.z, b2);
                b3 = fmaf(qB[i].w, c.w, b3);
            }
            const int m = mb + mm;
            const float dotA = (a0 + a1) + (a2 + a3);
            const float dA = fmaf(-2.f, dotA, snA + smn);
            if (dA < dA2) {  // rare after warm-up; strict < keeps tie-break
                const bool lt0 = dA < dA0, lt1 = dA < dA1;
                dA2 = lt1 ? dA1 : dA;  iA2 = lt1 ? iA1 : m;
                dA1 = lt0 ? dA0 : (lt1 ? dA : dA1);
                iA1 = lt0 ? iA0 : (lt1 ? m : iA1);
                dA0 = lt0 ? dA : dA0;  iA0 = lt0 ? m : iA0;
            }
            const float dotB = (b0 + b1) + (b2 + b3);
            const float dB = fmaf(-2.f, dotB, snB + smn);
            if (dB < dB2) {
                const bool lt0 = dB < dB0, lt1 = dB < dB1;
                dB2 = lt1 ? dB1 : dB;  iB2 = lt1 ? iB1 : m;
                dB1 = lt0 ? dB0 : (lt1 ? dB : dB1);
                iB1 = lt0 ? iB0 : (lt1 ? m : iB1);
                dB0 = lt0 ? dB : dB0;  iB0 = lt0 ? m : iB0;
            }
        }
    }
    const size_t oA = (((size_t)b * SPLIT + s) * NN + nA) * 3;
    pd[oA] = dA0; pd[oA + 1] = dA1; pd[oA + 2] = dA2;
    pi[oA] = iA0; pi[oA + 1] = iA1; pi[oA + 2] = iA2;
    const size_t oB = (((size_t)b * SPLIT + s) * NN + nB) * 3;
    pd[oB] = dB0; pd[oB + 1] = dB1; pd[oB + 2] = dB2;
    pi[oB] = iB0; pi[oB + 1] = iB1; pi[oB + 2] = iB2;
}

// ---------------------------------------------------------------------------
// K3: merge SPLIT sorted top-3 lists -> final 3 indices, (d, idx) lexicographic
// Static indexing only (fully unrolled) so arrays stay in registers.
// ---------------------------------------------------------------------------
__global__ __launch_bounds__(256) void k_merge(const float* __restrict__ pd,
                                               const int* __restrict__ pi,
                                               int* __restrict__ fi) {
    const int t = blockIdx.x * 256 + threadIdx.x;
    if (t >= BB * NN) return;
    const int b = t / NN, n = t % NN;
    float dv[3 * SPLIT]; int iv[3 * SPLIT];
#pragma unroll
    for (int s = 0; s < SPLIT; ++s) {
        const size_t o = (((size_t)b * SPLIT + s) * NN + n) * 3;
#pragma unroll
        for (int r = 0; r < 3; ++r) {
            dv[s * 3 + r] = pd[o + r];
            iv[s * 3 + r] = pi[o + r];
        }
    }
    float bd = -FLT_MAX; int bi = -1;
#pragma unroll
    for (int r = 0; r < 3; ++r) {
        float cd = FLT_MAX; int ci = 0x7fffffff;
#pragma unroll
        for (int j = 0; j < 3 * SPLIT; ++j) {
            const bool gt_prev = (dv[j] > bd) || (dv[j] == bd && iv[j] > bi);
            const bool lt_cur = (dv[j] < cd) || (dv[j] == cd && iv[j] < ci);
            if (gt_prev && lt_cur) { cd = dv[j]; ci = iv[j]; }
        }
        fi[(size_t)t * 3 + r] = ci;
        bd = cd; bi = ci;
    }
}

// ---------------------------------------------------------------------------
// K4: gather neighbors + 1x3/stride-3 conv + bias + relu
// ---------------------------------------------------------------------------
__global__ __launch_bounds__(256) void k_conv(const float* __restrict__ xt,
                                              const int* __restrict__ fi,
                                              const float* __restrict__ W,
                                              const float* __restrict__ bias,
                                              float* __restrict__ out) {
    __shared__ float Wl[KNN][CC][COUT];  // 48 KB
    const int b = blockIdx.x, n0 = blockIdx.y * 64;
    const int tid = threadIdx.x;
    const int nl = tid & 63, g = tid >> 6;
    for (int t = tid; t < COUT * CC * KNN; t += 256) {
        const int co = t / (CC * KNN);
        const int rem = t % (CC * KNN);
        const int c = rem / KNN, k = rem % KNN;
        Wl[k][c][co] = W[t];
    }
    __syncthreads();

    const int cobase = g * 16;
    float4 acc[4];
#pragma unroll
    for (int j = 0; j < 4; ++j) acc[j] = *(const float4*)&bias[cobase + j * 4];

    const size_t fbase = ((size_t)b * NN + n0 + nl) * 3;
#pragma unroll
    for (int k = 0; k < KNN; ++k) {
        const int src = fi[fbase + k];
        const float4* vrow = (const float4*)(xt + ((size_t)b * NN + src) * CC);
#pragma unroll
        for (int c4 = 0; c4 < 16; ++c4) {
            const float4 p = vrow[c4];
#pragma unroll
            for (int cp = 0; cp < 4; ++cp) {
                const float pv = (&p.x)[cp];
                const float4* wr = (const float4*)&Wl[k][c4 * 4 + cp][cobase];
#pragma unroll
                for (int j = 0; j < 4; ++j) {
                    const float4 w = wr[j];
                    acc[j].x = fmaf(pv, w.x, acc[j].x);
                    acc[j].y = fmaf(pv, w.y, acc[j].y);
                    acc[j].z = fmaf(pv, w.z, acc[j].z);
                    acc[j].w = fmaf(pv, w.w, acc[j].w);
                }
            }
        }
    }
#pragma unroll
    for (int j = 0; j < 4; ++j) {
#pragma unroll
        for (int cp = 0; cp < 4; ++cp) {
            const int co = cobase + j * 4 + cp;
            const float v = fmaxf((&acc[j].x)[cp], 0.f);
            out[((size_t)b * COUT + co) * NN + n0 + nl] = v;
        }
    }
}

extern "C" void kernel_launch(void* const* d_in, const int* in_sizes, int n_in,
                              void* d_out, int out_size, void* d_ws, size_t ws_size,
                              hipStream_t stream) {
    const float* x = (const float*)d_in[0];
    const float* W = (const float*)d_in[1];
    const float* bias = (const float*)d_in[2];
    float* out = (float*)d_out;

    char* ws = (char*)d_ws;
    float* xt = (float*)(ws);                   //  8,388,608 B
    float* nrm = (float*)(ws + 8388608);        //    131,072 B
    float* pd = (float*)(ws + 8519680);         //  3,145,728 B
    int* pi = (int*)(ws + 11665408);            //  3,145,728 B
    int* fi = (int*)(ws + 14811136);            //    393,216 B (total ~14.5 MB)

    k_prep<<<dim3(BB, NN / 64), 256, 0, stream>>>(x, xt, nrm);
    k_top3<<<dim3(BB, NN / (256 * QT), SPLIT), 256, 0, stream>>>(xt, nrm, pd, pi);
    k_merge<<<(BB * NN + 255) / 256, 256, 0, stream>>>(pd, pi, fi);
    k_conv<<<dim3(BB, NN / 64), 256, 0, stream>>>(xt, fi, W, bias, out);
}